// Round 4
// baseline (432.049 us; speedup 1.0000x reference)
//
#include <hip/hip_runtime.h>
#include <hip/hip_bf16.h>

#define N_NODES 100000
#define N_EDGES 1600000
#define N_FEAT 128
#define HID 64
#define N_GRAPHS 64
#define N_OUT 10
#define SCAN_B 1024
#define NBLK ((N_NODES + SCAN_B - 1) / SCAN_B)  // 98
#define SRCS_CAP (N_EDGES + 8 * N_NODES)  // CSR upper bound

typedef __attribute__((ext_vector_type(8))) short bf8_t;   // 8 bf16 in 4 VGPRs
typedef __attribute__((ext_vector_type(4))) float f4_t;    // MFMA accumulator
typedef __attribute__((ext_vector_type(2))) float f2_t;

__device__ __forceinline__ short f2bf(float f) {
    __hip_bfloat16 h = __float2bfloat16(f);
    return *(short*)&h;
}
__device__ __forceinline__ float bf2f(unsigned short u) {
    unsigned v = ((unsigned)u) << 16;
    return __builtin_bit_cast(float, v);
}
__device__ __forceinline__ unsigned char f2fp8(float v) {
    int p = __builtin_amdgcn_cvt_pk_fp8_f32(v, v, 0, false);
    return (unsigned char)(p & 0xFF);
}
// decode one dword of fp8 into two f2_t accumulators (v_pk_add_f32-friendly)
__device__ __forceinline__ void fp8acc2(f2_t* acc2, unsigned w) {
    acc2[0] += __builtin_amdgcn_cvt_pk_f32_fp8((int)w, false);
    acc2[1] += __builtin_amdgcn_cvt_pk_f32_fp8((int)w, true);
}

__device__ __forceinline__ int ldidx(const int* raw, int f, size_t i) {
    return f ? raw[2 * i] : raw[i];
}

// ---------- init: index dtype probe + zero indeg/sums/cnts ----------
__global__ __launch_bounds__(256) void k_init(const int* raw, int* flag, int* indeg,
                                              float* sums, float* cnts) {
    if (blockIdx.x == 0) {
        __shared__ int any;
        if (threadIdx.x == 0) any = 0;
        __syncthreads();
        int v = raw[2 * threadIdx.x + 1] | raw[2 * (threadIdx.x + 256) + 1] |
                raw[2 * (threadIdx.x + 512) + 1] | raw[2 * (threadIdx.x + 768) + 1];
        if (v != 0) any = 1;
        __syncthreads();
        if (threadIdx.x == 0) *flag = (any == 0) ? 1 : 0;
    }
    if (blockIdx.x == 1) {
        for (int i = threadIdx.x; i < N_GRAPHS * HID; i += 256) sums[i] = 0.f;
        for (int i = threadIdx.x; i < N_GRAPHS; i += 256) cnts[i] = 0.f;
    }
    for (int i = blockIdx.x * 256 + threadIdx.x; i < N_NODES; i += gridDim.x * 256)
        indeg[i] = 0;
}

// ---------- histogram via global atomics (vectorized col loads) ----------
__global__ __launch_bounds__(256) void k_hist2(const int* ei, const int* flag,
                                               int* indeg) {
    int f = *flag;
    int e = (blockIdx.x * 256 + threadIdx.x) * 4;
    if (e >= N_EDGES) return;
    int c[4];
    if (f) {  // int64 input: (lo,hi) pairs, hi==0
        const int4* p = (const int4*)(ei + 2 * ((size_t)N_EDGES + e));
        int4 a = p[0], b = p[1];
        c[0] = a.x; c[1] = a.z; c[2] = b.x; c[3] = b.z;
    } else {
        int4 a = *(const int4*)(ei + (size_t)N_EDGES + e);
        c[0] = a.x; c[1] = a.y; c[2] = a.z; c[3] = a.w;
    }
#pragma unroll
    for (int i = 0; i < 4; i++)
        if ((unsigned)c[i] < N_NODES) atomicAdd(&indeg[c[i]], 1);
}

// ---------- prefix scan over degrees (+ dis folded in) ----------
__global__ __launch_bounds__(SCAN_B) void k_scan1(const int* indeg, int* incl, int* bsum,
                                                  float* dis) {
    __shared__ int tmp[SCAN_B];
    int i = blockIdx.x * SCAN_B + threadIdx.x;
    int d0 = (i < N_NODES) ? indeg[i] : 0;
    tmp[threadIdx.x] = d0;
    if (i < N_NODES) dis[i] = rsqrtf((float)d0 + 1.0f);
    __syncthreads();
    for (int d = 1; d < SCAN_B; d <<= 1) {
        int t = (threadIdx.x >= d) ? tmp[threadIdx.x - d] : 0;
        __syncthreads();
        tmp[threadIdx.x] += t;
        __syncthreads();
    }
    if (i < N_NODES) incl[i] = tmp[threadIdx.x];
    if (threadIdx.x == SCAN_B - 1) bsum[blockIdx.x] = tmp[threadIdx.x];
}

__global__ void k_scan2(int* bsum) {
    __shared__ int tmp[128];
    tmp[threadIdx.x] = (threadIdx.x < NBLK) ? bsum[threadIdx.x] : 0;
    __syncthreads();
    for (int d = 1; d < 128; d <<= 1) {
        int t = (threadIdx.x >= d) ? tmp[threadIdx.x - d] : 0;
        __syncthreads();
        tmp[threadIdx.x] += t;
        __syncthreads();
    }
    if (threadIdx.x < NBLK) bsum[threadIdx.x] = tmp[threadIdx.x];
}

__global__ __launch_bounds__(SCAN_B) void k_scan3(const int* indeg, const int* incl,
                                                  const int* bsum, int* offs, int* cur) {
    int i = blockIdx.x * SCAN_B + threadIdx.x;
    if (i < N_NODES) {
        int pre = (blockIdx.x > 0) ? bsum[blockIdx.x - 1] : 0;
        int o = incl[i] - indeg[i] + pre;
        offs[i] = o;
        cur[i] = o;
    }
}

// ---------- CSR placement via global atomic cursors ----------
__global__ __launch_bounds__(256) void k_place2(const int* ei, const int* flag,
                                                int* cur, int* srcs) {
    int f = *flag;
    int e = (blockIdx.x * 256 + threadIdx.x) * 4;
    if (e >= N_EDGES) return;
    int c[4], s[4];
    if (f) {
        const int4* pc = (const int4*)(ei + 2 * ((size_t)N_EDGES + e));
        int4 a = pc[0], b = pc[1];
        c[0] = a.x; c[1] = a.z; c[2] = b.x; c[3] = b.z;
        const int4* ps = (const int4*)(ei + 2 * (size_t)e);
        int4 u = ps[0], v = ps[1];
        s[0] = u.x; s[1] = u.z; s[2] = v.x; s[3] = v.z;
    } else {
        int4 a = *(const int4*)(ei + (size_t)N_EDGES + e);
        c[0] = a.x; c[1] = a.y; c[2] = a.z; c[3] = a.w;
        int4 u = *(const int4*)(ei + (size_t)e);
        s[0] = u.x; s[1] = u.y; s[2] = u.z; s[3] = u.w;
    }
#pragma unroll
    for (int i = 0; i < 4; i++)
        if ((unsigned)c[i] < N_NODES) {
            // invalid src -> pad row (zeros) keeps placed-count == indeg
            int sv = ((unsigned)s[i] < N_NODES) ? s[i] : (int)N_NODES;
            int p = atomicAdd(&cur[c[i]], 1);
            srcs[p] = sv;
        }
}

// ---------- projection via MFMA: g[i,:] = fp8( dis[i] * (h[i,:] @ W) ) ----------
template <int K, typename IT>
__global__ __launch_bounds__(256) void k_proj(const IT* __restrict__ in,
                                              const float* __restrict__ W,
                                              const float* __restrict__ dis,
                                              unsigned char* __restrict__ g) {
    // zero the pad row (row N_NODES, 64 B) -- OOB edge slots in k_agg read it
    if (blockIdx.x == 0 && threadIdx.x < 16)
        ((unsigned*)g)[N_NODES * 16 + threadIdx.x] = 0u;
    const int NS = K / 32;
    int wave = threadIdx.x >> 6, lane = threadIdx.x & 63;
    int m = lane & 15, quad = lane >> 4;
    bf8_t Bf[NS][4];
#pragma unroll
    for (int s = 0; s < NS; s++)
#pragma unroll
        for (int t = 0; t < 4; t++)
#pragma unroll
            for (int j = 0; j < 8; j++)
                Bf[s][t][j] = f2bf(W[(s * 32 + quad * 8 + j) * 64 + t * 16 + m]);

    const int nchunks = N_NODES / 16;  // 6250
    const int stride = gridDim.x * 4;
    for (int chunk = blockIdx.x * 4 + wave; chunk < nchunks; chunk += stride) {
        int r0 = chunk * 16;
        const IT* src = in + (size_t)(r0 + m) * K + quad * 8;
        f4_t acc[4] = {{0.f, 0.f, 0.f, 0.f}, {0.f, 0.f, 0.f, 0.f},
                       {0.f, 0.f, 0.f, 0.f}, {0.f, 0.f, 0.f, 0.f}};
#pragma unroll
        for (int s = 0; s < NS; s++) {
            bf8_t a;
            if constexpr (sizeof(IT) == 2) {
                // bf16 input: fragment is a contiguous 16 B -- direct vector load
                a = *(const bf8_t*)(src + s * 32);
            } else {
                // fp32 input: two float4 loads + convert
                const float4* sp = (const float4*)(src + s * 32);
                float4 u0 = sp[0], u1 = sp[1];
                a[0] = f2bf(u0.x); a[1] = f2bf(u0.y); a[2] = f2bf(u0.z); a[3] = f2bf(u0.w);
                a[4] = f2bf(u1.x); a[5] = f2bf(u1.y); a[6] = f2bf(u1.z); a[7] = f2bf(u1.w);
            }
#pragma unroll
            for (int t = 0; t < 4; t++)
                acc[t] = __builtin_amdgcn_mfma_f32_16x16x32_bf16(a, Bf[s][t], acc[t], 0, 0, 0);
        }
        float dv[4];
#pragma unroll
        for (int i = 0; i < 4; i++) dv[i] = dis[r0 + quad * 4 + i];
#pragma unroll
        for (int t = 0; t < 4; t++)
#pragma unroll
            for (int i = 0; i < 4; i++)
                g[(size_t)(r0 + quad * 4 + i) * 64 + t * 16 + m] = f2fp8(dv[i] * acc[t][i]);
    }
}

// ---------- CSR aggregation: 8 nodes per wave, 8 lanes (= feature groups) per node ----------
// Lane (grp, fg) accumulates features fg*8..fg*8+7 of its node serially over edges.
// No cross-lane reduction needed; 8 fg lanes coalesce each 64 B fp8 row.
// OOB edge slots (past deg, up to wave-max) read the zeroed pad row (L1-hot).
template <bool RELU>
__global__ __launch_bounds__(256) void k_agg(const unsigned char* __restrict__ g,
                                             const int* __restrict__ srcs,
                                             const int* __restrict__ offs,
                                             const int* __restrict__ indeg,
                                             const float* __restrict__ dis,
                                             const float* __restrict__ b,
                                             unsigned short* __restrict__ out) {
    int node = (blockIdx.x * 256 + threadIdx.x) >> 3;
    int fg = threadIdx.x & 7;
    if (node >= N_NODES) return;
    int beg = offs[node];
    int deg = indeg[node];
    // wave-wide max degree (deg is uniform within each 8-lane group)
    int mx = deg;
    mx = max(mx, __shfl_xor(mx, 8));
    mx = max(mx, __shfl_xor(mx, 16));
    mx = max(mx, __shfl_xor(mx, 32));
    const unsigned char* gf = g + fg * 8;
    f2_t acc2[4] = {{0.f, 0.f}, {0.f, 0.f}, {0.f, 0.f}, {0.f, 0.f}};
    {  // self loop
        uint2 w = *(const uint2*)(gf + (size_t)node * 64);
        fp8acc2(acc2, w.x);
        fp8acc2(acc2 + 2, w.y);
    }
    for (int e0 = 0; e0 < mx; e0 += 8) {
        // lane fg fetches source of edge e0+fg for its group (pad row if past deg)
        int sv = (e0 + fg < deg) ? srcs[beg + e0 + fg] : (int)N_NODES;
        // broadcast within 8-lane group: BitMode offset = (k<<5)|and_mask(0x18)
#define AGG_STEP(kk)                                                          \
        {                                                                     \
            int s = __builtin_amdgcn_ds_swizzle(sv, ((kk) << 5) | 0x18);      \
            uint2 w = *(const uint2*)(gf + (size_t)s * 64);                   \
            fp8acc2(acc2, w.x);                                               \
            fp8acc2(acc2 + 2, w.y);                                           \
        }
        AGG_STEP(0) AGG_STEP(1) AGG_STEP(2) AGG_STEP(3)
        AGG_STEP(4) AGG_STEP(5) AGG_STEP(6) AGG_STEP(7)
#undef AGG_STEP
    }
    float dv = dis[node];
    unsigned o[4];
#pragma unroll
    for (int p = 0; p < 4; p++) {
        float v0 = dv * acc2[p][0] + b[fg * 8 + 2 * p];
        float v1 = dv * acc2[p][1] + b[fg * 8 + 2 * p + 1];
        if (RELU) { v0 = fmaxf(v0, 0.f); v1 = fmaxf(v1, 0.f); }
        o[p] = ((unsigned)(unsigned short)f2bf(v1) << 16) | (unsigned short)f2bf(v0);
    }
    *(uint4*)((char*)out + (size_t)node * 128 + fg * 16) =
        make_uint4(o[0], o[1], o[2], o[3]);
}

// ---------- pooling: 4 blocks per graph, binary-search boundaries, LDS reduce ----------
__global__ __launch_bounds__(256) void k_pool(const unsigned short* h, const int* bat,
                                              const int* flag, float* sums, float* cnts) {
    __shared__ int sb[2];
    __shared__ float red[4][64];
    int g = blockIdx.x >> 2;
    int q = blockIdx.x & 3;
    if (threadIdx.x == 0) {
        int f = *flag;
        int lo = 0, hi = N_NODES;
        while (lo < hi) { int mid = (lo + hi) >> 1; if (ldidx(bat, f, (size_t)mid) < g) lo = mid + 1; else hi = mid; }
        sb[0] = lo;
        hi = N_NODES;
        while (lo < hi) { int mid = (lo + hi) >> 1; if (ldidx(bat, f, (size_t)mid) < g + 1) lo = mid + 1; else hi = mid; }
        sb[1] = lo;
    }
    __syncthreads();
    int gs = sb[0], ge = sb[1];
    int len = ge - gs;
    if (q == 0 && threadIdx.x == 0) cnts[g] = (float)len;
    if (len == 0) return;
    int qlen = (len + 3) >> 2;
    int beg = gs + q * qlen, end = min(ge, beg + qlen);
    int wave = threadIdx.x >> 6, lane = threadIdx.x & 63;
    float acc = 0.f;
    for (int r = beg + wave; r < end; r += 4)
        acc += bf2f(h[(size_t)r * 64 + lane]);
    red[wave][lane] = acc;
    __syncthreads();
    if (threadIdx.x < 64) {
        float v = red[0][threadIdx.x] + red[1][threadIdx.x] +
                  red[2][threadIdx.x] + red[3][threadIdx.x];
        atomicAdd(&sums[g * 64 + threadIdx.x], v);
    }
}

// ---------- head ----------
__global__ void k_head(const float* sums, const float* cnts, const float* Wlin,
                       const float* blin, float* out) {
    int t = blockIdx.x * 64 + threadIdx.x;
    if (t < N_GRAPHS * N_OUT) {
        int gph = t / N_OUT, o = t % N_OUT;
        float c = fmaxf(cnts[gph], 1.0f);
        float a = 0.f;
        for (int j = 0; j < HID; j++) a += sums[gph * 64 + j] * Wlin[j * N_OUT + o];
        out[t] = a / c + blin[o];
    }
}

extern "C" void kernel_launch(void* const* d_in, const int* in_sizes, int n_in,
                              void* d_out, int out_size, void* d_ws, size_t ws_size,
                              hipStream_t stream) {
    const float *x = nullptr, *W1 = nullptr, *W2 = nullptr, *W3 = nullptr, *Wlin = nullptr;
    const float *b1 = nullptr, *b2 = nullptr, *b3 = nullptr, *blin = nullptr;
    const int *ei = nullptr, *bat = nullptr;
    int n4096 = 0, n64 = 0;
    for (int i = 0; i < n_in; i++) {
        switch (in_sizes[i]) {
            case N_NODES * N_FEAT:  x    = (const float*)d_in[i]; break;
            case 2 * N_EDGES:       ei   = (const int*)d_in[i];   break;
            case N_NODES:           bat  = (const int*)d_in[i];   break;
            case N_FEAT * HID:      W1   = (const float*)d_in[i]; break;
            case HID * HID:
                if (n4096++ == 0) W2 = (const float*)d_in[i];
                else              W3 = (const float*)d_in[i];
                break;
            case HID * N_OUT:       Wlin = (const float*)d_in[i]; break;
            case HID:
                if (n64 == 0) b1 = (const float*)d_in[i];
                else if (n64 == 1) b2 = (const float*)d_in[i];
                else b3 = (const float*)d_in[i];
                n64++;
                break;
            case N_OUT:             blin = (const float*)d_in[i]; break;
            default: break;
        }
    }
    if (!x || !ei || !bat || !W1 || !W2 || !W3 || !Wlin || !b1 || !b2 || !b3 || !blin) {
        x    = (const float*)d_in[0];
        ei   = (const int*)d_in[1];
        bat  = (const int*)d_in[2];
        W1   = (const float*)d_in[3];  b1   = (const float*)d_in[4];
        W2   = (const float*)d_in[5];  b2   = (const float*)d_in[6];
        W3   = (const float*)d_in[7];  b3   = (const float*)d_in[8];
        Wlin = (const float*)d_in[9];  blin = (const float*)d_in[10];
    }
    float* out = (float*)d_out;  // fp32 output

    char* ws = (char*)d_ws;
    size_t off = 0;
    unsigned short* A     = (unsigned short*)(ws + off); off += (size_t)N_NODES * 64 * 2;
    unsigned char*  G     = (unsigned char*)(ws + off);  off += (size_t)(N_NODES + 1) * 64;
    float*          dis   = (float*)(ws + off);          off += (size_t)N_NODES * 4;
    float*          sums  = (float*)(ws + off);          off += (size_t)N_GRAPHS * HID * 4;
    float*          cnts  = (float*)(ws + off);          off += (size_t)N_GRAPHS * 4;
    int*            indeg = (int*)(ws + off);            off += (size_t)N_NODES * 4;
    int*            incl  = (int*)(ws + off);            off += (size_t)N_NODES * 4;
    int*            offs  = (int*)(ws + off);            off += (size_t)N_NODES * 4;
    int*            cur   = (int*)(ws + off);            off += (size_t)N_NODES * 4;
    int*            bsum  = (int*)(ws + off);            off += 128 * 4;
    int*            srcs  = (int*)(ws + off);            off += (size_t)SRCS_CAP * 4;
    int*            flag  = (int*)(ws + off);            off += 4;

    const int nb_agg   = (N_NODES * 8 + 255) / 256;     // 3125 (8 lanes per node)
    const int nb_edge4 = (N_EDGES / 4 + 255) / 256;     // 1563

    // init: flag detect + zero indeg/sums/cnts
    k_init<<<64, 256, 0, stream>>>(ei, flag, indeg, sums, cnts);

    // --- CSR build: atomic hist -> scan(+dis) -> atomic place ---
    k_hist2<<<nb_edge4, 256, 0, stream>>>(ei, flag, indeg);
    k_scan1<<<NBLK, SCAN_B, 0, stream>>>(indeg, incl, bsum, dis);
    k_scan2<<<1, 128, 0, stream>>>(bsum);
    k_scan3<<<NBLK, SCAN_B, 0, stream>>>(indeg, incl, bsum, offs, cur);
    k_place2<<<nb_edge4, 256, 0, stream>>>(ei, flag, cur, srcs);

    // conv1: x(fp32,128) -> G(fp8) -> A(bf16)
    k_proj<128, float><<<512, 256, 0, stream>>>(x, W1, dis, G);
    k_agg<true><<<nb_agg, 256, 0, stream>>>(G, srcs, offs, indeg, dis, b1, A);

    // conv2: A -> G -> A
    k_proj<64, unsigned short><<<512, 256, 0, stream>>>(A, W2, dis, G);
    k_agg<true><<<nb_agg, 256, 0, stream>>>(G, srcs, offs, indeg, dis, b2, A);

    // conv3: A -> G -> A (no relu)
    k_proj<64, unsigned short><<<512, 256, 0, stream>>>(A, W3, dis, G);
    k_agg<false><<<nb_agg, 256, 0, stream>>>(G, srcs, offs, indeg, dis, b3, A);

    // pool + head (sums/cnts pre-zeroed in k_init)
    k_pool<<<N_GRAPHS * 4, 256, 0, stream>>>(A, bat, flag, sums, cnts);
    k_head<<<(N_GRAPHS * N_OUT + 63) / 64, 64, 0, stream>>>(sums, cnts, Wlin, blin, out);
}

// Round 5
// 324.409 us; speedup vs baseline: 1.3318x; 1.3318x over previous
//
#include <hip/hip_runtime.h>
#include <hip/hip_bf16.h>

#define N_NODES 100000
#define N_EDGES 1600000
#define N_FEAT 128
#define HID 64
#define N_GRAPHS 64
#define N_OUT 10
#define SCAN_B 1024
#define NBLK ((N_NODES + SCAN_B - 1) / SCAN_B)  // 98
#define NBUCK 256
#define RANGEB ((N_NODES + NBUCK - 1) / NBUCK)  // 391
#define CAP 8192
#define SRCS_CAP (N_EDGES + 8 * N_NODES)  // CSR upper bound

typedef __attribute__((ext_vector_type(8))) short bf8_t;   // 8 bf16 in 4 VGPRs
typedef __attribute__((ext_vector_type(4))) float f4_t;    // MFMA accumulator
typedef __attribute__((ext_vector_type(2))) float f2_t;

__device__ __forceinline__ short f2bf(float f) {
    __hip_bfloat16 h = __float2bfloat16(f);
    return *(short*)&h;
}
__device__ __forceinline__ float bf2f(unsigned short u) {
    unsigned v = ((unsigned)u) << 16;
    return __builtin_bit_cast(float, v);
}
__device__ __forceinline__ unsigned char f2fp8(float v) {
    int p = __builtin_amdgcn_cvt_pk_fp8_f32(v, v, 0, false);
    return (unsigned char)(p & 0xFF);
}
// decode one dword of fp8 into two f2_t accumulators (v_pk_add_f32-friendly)
__device__ __forceinline__ void fp8acc2(f2_t* acc2, unsigned w) {
    acc2[0] += __builtin_amdgcn_cvt_pk_f32_fp8((int)w, false);
    acc2[1] += __builtin_amdgcn_cvt_pk_f32_fp8((int)w, true);
}

__device__ __forceinline__ int ldidx(const int* raw, int f, size_t i) {
    return f ? raw[2 * i] : raw[i];
}

// ---------- index dtype probe + workspace zeroing (merged) ----------
__global__ void k_detect(const int* raw, int* flag, int* bcnt, float* sums, float* cnts) {
    __shared__ int any;
    if (threadIdx.x == 0) any = 0;
    __syncthreads();
    int v = raw[2 * threadIdx.x + 1] | raw[2 * (threadIdx.x + 256) + 1] |
            raw[2 * (threadIdx.x + 512) + 1] | raw[2 * (threadIdx.x + 768) + 1];
    if (v != 0) any = 1;
    __syncthreads();
    if (threadIdx.x == 0) *flag = (any == 0) ? 1 : 0;
    for (int i = threadIdx.x; i < NBUCK; i += 256) bcnt[i] = 0;
    for (int i = threadIdx.x; i < N_GRAPHS * HID; i += 256) sums[i] = 0.f;
    for (int i = threadIdx.x; i < N_GRAPHS; i += 256) cnts[i] = 0.f;
}

// ---------- phase 1: bin edges into 256 col-range buckets (packed 4B entries) ----------
// entry = (local_col << 17) | src   (local_col < 391 -> 9 bits, src <= 100000 -> 17 bits)
__global__ __launch_bounds__(256) void k_bucket(const int* ei, const int* flag,
                                                int* pairs, int* cnt) {
    __shared__ int lcnt[NBUCK];
    __shared__ int gbase[NBUCK];
    int f = *flag;
    if (threadIdx.x < NBUCK) lcnt[threadIdx.x] = 0;
    __syncthreads();
    int base = blockIdx.x * 2048;
    int r[8], lpos[8], c[8], s[8];
#pragma unroll
    for (int i = 0; i < 8; i++) {
        int e = base + i * 256 + threadIdx.x;
        r[i] = -1;
        if (e < N_EDGES) {
            c[i] = ldidx(ei, f, (size_t)N_EDGES + e);
            s[i] = ldidx(ei, f, (size_t)e);
            if ((unsigned)c[i] < N_NODES && (unsigned)s[i] < N_NODES) {
                r[i] = c[i] / RANGEB;
                lpos[i] = atomicAdd(&lcnt[r[i]], 1);
            }
        }
    }
    __syncthreads();
    if (threadIdx.x < NBUCK && lcnt[threadIdx.x] > 0)
        gbase[threadIdx.x] = atomicAdd(&cnt[threadIdx.x], lcnt[threadIdx.x]);
    __syncthreads();
#pragma unroll
    for (int i = 0; i < 8; i++) {
        if (r[i] >= 0) {
            int p = gbase[r[i]] + lpos[i];
            if (p < CAP) {
                int loc = c[i] - r[i] * RANGEB;
                pairs[(size_t)r[i] * CAP + p] = (loc << 17) | s[i];
            }
        }
    }
}

// ---------- per-bucket LDS histogram -> indeg + dis (merged) ----------
__global__ __launch_bounds__(1024) void k_hist(const int* pairs, const int* cnt,
                                               int* indeg, float* dis) {
    __shared__ int hist[RANGEB];
    int b = blockIdx.x;
    int c0 = b * RANGEB;
    int range = min(RANGEB, N_NODES - c0);
    for (int i = threadIdx.x; i < range; i += 1024) hist[i] = 0;
    __syncthreads();
    int n = min(cnt[b], CAP);
    const int* pb = pairs + (size_t)b * CAP;
    for (int i = threadIdx.x; i < n; i += 1024)
        atomicAdd(&hist[pb[i] >> 17], 1);
    __syncthreads();
    for (int i = threadIdx.x; i < range; i += 1024) {
        int d = hist[i];
        indeg[c0 + i] = d;
        dis[c0 + i] = rsqrtf((float)d + 1.0f);
    }
}

// ---------- prefix scan over UNPADDED degrees ----------
__global__ __launch_bounds__(SCAN_B) void k_scan1(const int* indeg, int* incl, int* bsum) {
    __shared__ int tmp[SCAN_B];
    int i = blockIdx.x * SCAN_B + threadIdx.x;
    tmp[threadIdx.x] = (i < N_NODES) ? indeg[i] : 0;
    __syncthreads();
    for (int d = 1; d < SCAN_B; d <<= 1) {
        int t = (threadIdx.x >= d) ? tmp[threadIdx.x - d] : 0;
        __syncthreads();
        tmp[threadIdx.x] += t;
        __syncthreads();
    }
    if (i < N_NODES) incl[i] = tmp[threadIdx.x];
    if (threadIdx.x == SCAN_B - 1) bsum[blockIdx.x] = tmp[threadIdx.x];
}

__global__ void k_scan2(int* bsum) {
    __shared__ int tmp[128];
    tmp[threadIdx.x] = (threadIdx.x < NBLK) ? bsum[threadIdx.x] : 0;
    __syncthreads();
    for (int d = 1; d < 128; d <<= 1) {
        int t = (threadIdx.x >= d) ? tmp[threadIdx.x - d] : 0;
        __syncthreads();
        tmp[threadIdx.x] += t;
        __syncthreads();
    }
    if (threadIdx.x < NBLK) bsum[threadIdx.x] = tmp[threadIdx.x];
}

__global__ __launch_bounds__(SCAN_B) void k_scan3(const int* indeg, const int* incl,
                                                  const int* bsum, int* offs) {
    int i = blockIdx.x * SCAN_B + threadIdx.x;
    if (i < N_NODES) {
        int pre = (blockIdx.x > 0) ? bsum[blockIdx.x - 1] : 0;
        offs[i] = incl[i] - indeg[i] + pre;
    }
}

// ---------- per-bucket CSR placement via LDS cursors ----------
__global__ __launch_bounds__(1024) void k_place3(const int* pairs, const int* cnt,
                                                 const int* offs, int* srcs) {
    __shared__ int cur[RANGEB];
    int b = blockIdx.x;
    int c0 = b * RANGEB;
    int range = min(RANGEB, N_NODES - c0);
    for (int i = threadIdx.x; i < range; i += 1024) cur[i] = 0;
    __syncthreads();
    int n = min(cnt[b], CAP);
    const int* pb = pairs + (size_t)b * CAP;
    for (int i = threadIdx.x; i < n; i += 1024) {
        int v = pb[i];
        int loc = v >> 17;
        int p = offs[c0 + loc] + atomicAdd(&cur[loc], 1);
        srcs[p] = v & 0x1FFFF;
    }
}

// ---------- projection via MFMA: g[i,:] = fp8( dis[i] * (h[i,:] @ W) ) ----------
template <int K, typename IT>
__global__ __launch_bounds__(256) void k_proj(const IT* __restrict__ in,
                                              const float* __restrict__ W,
                                              const float* __restrict__ dis,
                                              unsigned char* __restrict__ g) {
    // zero the pad row (row N_NODES, 64 B) -- OOB edge slots in aggregation read it
    if (blockIdx.x == 0 && threadIdx.x < 16)
        ((unsigned*)g)[N_NODES * 16 + threadIdx.x] = 0u;
    const int NS = K / 32;
    int wave = threadIdx.x >> 6, lane = threadIdx.x & 63;
    int m = lane & 15, quad = lane >> 4;
    bf8_t Bf[NS][4];
#pragma unroll
    for (int s = 0; s < NS; s++)
#pragma unroll
        for (int t = 0; t < 4; t++)
#pragma unroll
            for (int j = 0; j < 8; j++)
                Bf[s][t][j] = f2bf(W[(s * 32 + quad * 8 + j) * 64 + t * 16 + m]);

    const int nchunks = N_NODES / 16;  // 6250
    const int stride = gridDim.x * 4;
    for (int chunk = blockIdx.x * 4 + wave; chunk < nchunks; chunk += stride) {
        int r0 = chunk * 16;
        const IT* src = in + (size_t)(r0 + m) * K + quad * 8;
        f4_t acc[4] = {{0.f, 0.f, 0.f, 0.f}, {0.f, 0.f, 0.f, 0.f},
                       {0.f, 0.f, 0.f, 0.f}, {0.f, 0.f, 0.f, 0.f}};
#pragma unroll
        for (int s = 0; s < NS; s++) {
            bf8_t a;
            if constexpr (sizeof(IT) == 2) {
                a = *(const bf8_t*)(src + s * 32);
            } else {
                const float4* sp = (const float4*)(src + s * 32);
                float4 u0 = sp[0], u1 = sp[1];
                a[0] = f2bf(u0.x); a[1] = f2bf(u0.y); a[2] = f2bf(u0.z); a[3] = f2bf(u0.w);
                a[4] = f2bf(u1.x); a[5] = f2bf(u1.y); a[6] = f2bf(u1.z); a[7] = f2bf(u1.w);
            }
#pragma unroll
            for (int t = 0; t < 4; t++)
                acc[t] = __builtin_amdgcn_mfma_f32_16x16x32_bf16(a, Bf[s][t], acc[t], 0, 0, 0);
        }
        float dv[4];
#pragma unroll
        for (int i = 0; i < 4; i++) dv[i] = dis[r0 + quad * 4 + i];
#pragma unroll
        for (int t = 0; t < 4; t++)
#pragma unroll
            for (int i = 0; i < 4; i++)
                g[(size_t)(r0 + quad * 4 + i) * 64 + t * 16 + m] = f2fp8(dv[i] * acc[t][i]);
    }
}

// ---------- FUSED agg + next-layer projection ----------
// 16 nodes per wave, 4 lanes per node (lane c holds feats c*16..c*16+15).
// After bias+relu the wave's 16 h-rows go through LDS into MFMA fragments
// (identical layout to k_proj) and the NEXT layer's G is written directly.
__global__ __launch_bounds__(256) void k_aggproj(const unsigned char* __restrict__ g,
                                                 const int* __restrict__ srcs,
                                                 const int* __restrict__ offs,
                                                 const int* __restrict__ indeg,
                                                 const float* __restrict__ dis,
                                                 const float* __restrict__ b,
                                                 const float* __restrict__ W,
                                                 unsigned char* __restrict__ gout) {
    // zero pad row of the OUTPUT G (read by the next aggregation)
    if (blockIdx.x == 0 && threadIdx.x < 16)
        ((unsigned*)gout)[N_NODES * 16 + threadIdx.x] = 0u;

    int wave = threadIdx.x >> 6, lane = threadIdx.x & 63;
    int m = lane & 15, quad = lane >> 4;

    // preload next-layer W fragments (same layout as k_proj<64>)
    bf8_t Bf[2][4];
#pragma unroll
    for (int s = 0; s < 2; s++)
#pragma unroll
        for (int t = 0; t < 4; t++)
#pragma unroll
            for (int j = 0; j < 8; j++)
                Bf[s][t][j] = f2bf(W[(s * 32 + quad * 8 + j) * 64 + t * 16 + m]);

    int grp = blockIdx.x * 64 + wave * 16;  // this wave's 16 nodes
    int nl = lane >> 2;                      // node-in-wave 0..15
    int c = lane & 3;                        // 16B chunk of the 64B row
    int node = grp + nl;
    bool valid = node < N_NODES;
    int beg = valid ? offs[node] : 0;
    int deg = valid ? indeg[node] : 0;
    int mx = deg;
    mx = max(mx, __shfl_xor(mx, 4));
    mx = max(mx, __shfl_xor(mx, 8));
    mx = max(mx, __shfl_xor(mx, 16));
    mx = max(mx, __shfl_xor(mx, 32));
    const unsigned char* gf = g + c * 16;
    f2_t acc2[8] = {{0.f,0.f},{0.f,0.f},{0.f,0.f},{0.f,0.f},
                    {0.f,0.f},{0.f,0.f},{0.f,0.f},{0.f,0.f}};
    {   // self loop (invalid nodes read the zeroed pad row)
        int self = valid ? node : (int)N_NODES;
        uint4 w = *(const uint4*)(gf + (size_t)self * 64);
        fp8acc2(acc2 + 0, w.x); fp8acc2(acc2 + 2, w.y);
        fp8acc2(acc2 + 4, w.z); fp8acc2(acc2 + 6, w.w);
    }
    for (int e0 = 0; e0 < mx; e0 += 4) {
        int sv = (e0 + c < deg) ? srcs[beg + e0 + c] : (int)N_NODES;
        // broadcast within 4-lane group: offset = (k<<5) | and_mask(0x1C)
#define AGJ_STEP(kk)                                                          \
        {                                                                     \
            int s = __builtin_amdgcn_ds_swizzle(sv, ((kk) << 5) | 0x1C);      \
            uint4 w = *(const uint4*)(gf + (size_t)s * 64);                   \
            fp8acc2(acc2 + 0, w.x); fp8acc2(acc2 + 2, w.y);                   \
            fp8acc2(acc2 + 4, w.z); fp8acc2(acc2 + 6, w.w);                   \
        }
        AGJ_STEP(0) AGJ_STEP(1) AGJ_STEP(2) AGJ_STEP(3)
#undef AGJ_STEP
    }
    // h = relu(dis*acc + b) -> bf16 pairs -> LDS (row stride 36 dwords)
    float dv = valid ? dis[node] : 0.f;
    unsigned hw[8];
#pragma unroll
    for (int p = 0; p < 8; p++) {
        float v0 = fmaxf(dv * acc2[p][0] + b[c * 16 + 2 * p], 0.f);
        float v1 = fmaxf(dv * acc2[p][1] + b[c * 16 + 2 * p + 1], 0.f);
        hw[p] = ((unsigned)(unsigned short)f2bf(v1) << 16) | (unsigned short)f2bf(v0);
    }
    __shared__ unsigned lds4[4 * 16 * 36];
    {
        int base = (wave * 16 + nl) * 36 + c * 8;
        *(uint4*)&lds4[base]     = make_uint4(hw[0], hw[1], hw[2], hw[3]);
        *(uint4*)&lds4[base + 4] = make_uint4(hw[4], hw[5], hw[6], hw[7]);
    }
    __syncthreads();
    // MFMA A-fragments: row m, k-offset quad*8 (same layout as k_proj)
    bf8_t a0 = __builtin_bit_cast(bf8_t, *(const uint4*)&lds4[(wave * 16 + m) * 36 + quad * 4]);
    bf8_t a1 = __builtin_bit_cast(bf8_t, *(const uint4*)&lds4[(wave * 16 + m) * 36 + 16 + quad * 4]);
    f4_t acc[4] = {{0.f, 0.f, 0.f, 0.f}, {0.f, 0.f, 0.f, 0.f},
                   {0.f, 0.f, 0.f, 0.f}, {0.f, 0.f, 0.f, 0.f}};
#pragma unroll
    for (int t = 0; t < 4; t++) {
        acc[t] = __builtin_amdgcn_mfma_f32_16x16x32_bf16(a0, Bf[0][t], acc[t], 0, 0, 0);
        acc[t] = __builtin_amdgcn_mfma_f32_16x16x32_bf16(a1, Bf[1][t], acc[t], 0, 0, 0);
    }
    int rbase = grp + quad * 4;
    float dv2[4];
#pragma unroll
    for (int i = 0; i < 4; i++)
        dv2[i] = (rbase + i < N_NODES) ? dis[rbase + i] : 0.f;
#pragma unroll
    for (int t = 0; t < 4; t++)
#pragma unroll
        for (int i = 0; i < 4; i++)
            if (rbase + i < N_NODES)
                gout[(size_t)(rbase + i) * 64 + t * 16 + m] = f2fp8(dv2[i] * acc[t][i]);
}

// ---------- plain CSR aggregation (final conv): 8 nodes/wave, 8 lanes/node ----------
template <bool RELU>
__global__ __launch_bounds__(256) void k_agg(const unsigned char* __restrict__ g,
                                             const int* __restrict__ srcs,
                                             const int* __restrict__ offs,
                                             const int* __restrict__ indeg,
                                             const float* __restrict__ dis,
                                             const float* __restrict__ b,
                                             unsigned short* __restrict__ out) {
    int node = (blockIdx.x * 256 + threadIdx.x) >> 3;
    int fg = threadIdx.x & 7;
    if (node >= N_NODES) return;
    int beg = offs[node];
    int deg = indeg[node];
    int mx = deg;
    mx = max(mx, __shfl_xor(mx, 8));
    mx = max(mx, __shfl_xor(mx, 16));
    mx = max(mx, __shfl_xor(mx, 32));
    const unsigned char* gf = g + fg * 8;
    f2_t acc2[4] = {{0.f, 0.f}, {0.f, 0.f}, {0.f, 0.f}, {0.f, 0.f}};
    {  // self loop
        uint2 w = *(const uint2*)(gf + (size_t)node * 64);
        fp8acc2(acc2, w.x);
        fp8acc2(acc2 + 2, w.y);
    }
    for (int e0 = 0; e0 < mx; e0 += 8) {
        int sv = (e0 + fg < deg) ? srcs[beg + e0 + fg] : (int)N_NODES;
#define AGG_STEP(kk)                                                          \
        {                                                                     \
            int s = __builtin_amdgcn_ds_swizzle(sv, ((kk) << 5) | 0x18);      \
            uint2 w = *(const uint2*)(gf + (size_t)s * 64);                   \
            fp8acc2(acc2, w.x);                                               \
            fp8acc2(acc2 + 2, w.y);                                           \
        }
        AGG_STEP(0) AGG_STEP(1) AGG_STEP(2) AGG_STEP(3)
        AGG_STEP(4) AGG_STEP(5) AGG_STEP(6) AGG_STEP(7)
#undef AGG_STEP
    }
    float dv = dis[node];
    unsigned o[4];
#pragma unroll
    for (int p = 0; p < 4; p++) {
        float v0 = dv * acc2[p][0] + b[fg * 8 + 2 * p];
        float v1 = dv * acc2[p][1] + b[fg * 8 + 2 * p + 1];
        if (RELU) { v0 = fmaxf(v0, 0.f); v1 = fmaxf(v1, 0.f); }
        o[p] = ((unsigned)(unsigned short)f2bf(v1) << 16) | (unsigned short)f2bf(v0);
    }
    *(uint4*)((char*)out + (size_t)node * 128 + fg * 16) =
        make_uint4(o[0], o[1], o[2], o[3]);
}

// ---------- pooling: 4 blocks per graph, binary-search boundaries, LDS reduce ----------
__global__ __launch_bounds__(256) void k_pool(const unsigned short* h, const int* bat,
                                              const int* flag, float* sums, float* cnts) {
    __shared__ int sb[2];
    __shared__ float red[4][64];
    int g = blockIdx.x >> 2;
    int q = blockIdx.x & 3;
    if (threadIdx.x == 0) {
        int f = *flag;
        int lo = 0, hi = N_NODES;
        while (lo < hi) { int mid = (lo + hi) >> 1; if (ldidx(bat, f, (size_t)mid) < g) lo = mid + 1; else hi = mid; }
        sb[0] = lo;
        hi = N_NODES;
        while (lo < hi) { int mid = (lo + hi) >> 1; if (ldidx(bat, f, (size_t)mid) < g + 1) lo = mid + 1; else hi = mid; }
        sb[1] = lo;
    }
    __syncthreads();
    int gs = sb[0], ge = sb[1];
    int len = ge - gs;
    if (q == 0 && threadIdx.x == 0) cnts[g] = (float)len;
    if (len == 0) return;
    int qlen = (len + 3) >> 2;
    int beg = gs + q * qlen, end = min(ge, beg + qlen);
    int wave = threadIdx.x >> 6, lane = threadIdx.x & 63;
    float acc = 0.f;
    for (int r = beg + wave; r < end; r += 4)
        acc += bf2f(h[(size_t)r * 64 + lane]);
    red[wave][lane] = acc;
    __syncthreads();
    if (threadIdx.x < 64) {
        float v = red[0][threadIdx.x] + red[1][threadIdx.x] +
                  red[2][threadIdx.x] + red[3][threadIdx.x];
        atomicAdd(&sums[g * 64 + threadIdx.x], v);
    }
}

// ---------- head ----------
__global__ void k_head(const float* sums, const float* cnts, const float* Wlin,
                       const float* blin, float* out) {
    int t = blockIdx.x * 64 + threadIdx.x;
    if (t < N_GRAPHS * N_OUT) {
        int gph = t / N_OUT, o = t % N_OUT;
        float c = fmaxf(cnts[gph], 1.0f);
        float a = 0.f;
        for (int j = 0; j < HID; j++) a += sums[gph * 64 + j] * Wlin[j * N_OUT + o];
        out[t] = a / c + blin[o];
    }
}

extern "C" void kernel_launch(void* const* d_in, const int* in_sizes, int n_in,
                              void* d_out, int out_size, void* d_ws, size_t ws_size,
                              hipStream_t stream) {
    const float *x = nullptr, *W1 = nullptr, *W2 = nullptr, *W3 = nullptr, *Wlin = nullptr;
    const float *b1 = nullptr, *b2 = nullptr, *b3 = nullptr, *blin = nullptr;
    const int *ei = nullptr, *bat = nullptr;
    int n4096 = 0, n64 = 0;
    for (int i = 0; i < n_in; i++) {
        switch (in_sizes[i]) {
            case N_NODES * N_FEAT:  x    = (const float*)d_in[i]; break;
            case 2 * N_EDGES:       ei   = (const int*)d_in[i];   break;
            case N_NODES:           bat  = (const int*)d_in[i];   break;
            case N_FEAT * HID:      W1   = (const float*)d_in[i]; break;
            case HID * HID:
                if (n4096++ == 0) W2 = (const float*)d_in[i];
                else              W3 = (const float*)d_in[i];
                break;
            case HID * N_OUT:       Wlin = (const float*)d_in[i]; break;
            case HID:
                if (n64 == 0) b1 = (const float*)d_in[i];
                else if (n64 == 1) b2 = (const float*)d_in[i];
                else b3 = (const float*)d_in[i];
                n64++;
                break;
            case N_OUT:             blin = (const float*)d_in[i]; break;
            default: break;
        }
    }
    if (!x || !ei || !bat || !W1 || !W2 || !W3 || !Wlin || !b1 || !b2 || !b3 || !blin) {
        x    = (const float*)d_in[0];
        ei   = (const int*)d_in[1];
        bat  = (const int*)d_in[2];
        W1   = (const float*)d_in[3];  b1   = (const float*)d_in[4];
        W2   = (const float*)d_in[5];  b2   = (const float*)d_in[6];
        W3   = (const float*)d_in[7];  b3   = (const float*)d_in[8];
        Wlin = (const float*)d_in[9];  blin = (const float*)d_in[10];
    }
    float* out = (float*)d_out;  // fp32 output

    char* ws = (char*)d_ws;
    size_t off = 0;
    int*            pairs = (int*)(ws + off);            off += (size_t)NBUCK * CAP * 4;
    unsigned short* A     = (unsigned short*)(ws + off); off += (size_t)N_NODES * 64 * 2;
    unsigned char*  Ga    = (unsigned char*)(ws + off);  off += (size_t)(N_NODES + 1) * 64;
    unsigned char*  Gb    = (unsigned char*)(ws + off);  off += (size_t)(N_NODES + 1) * 64;
    float*          dis   = (float*)(ws + off);          off += (size_t)N_NODES * 4;
    float*          sums  = (float*)(ws + off);          off += (size_t)N_GRAPHS * HID * 4;
    float*          cnts  = (float*)(ws + off);          off += (size_t)N_GRAPHS * 4;
    int*            indeg = (int*)(ws + off);            off += (size_t)N_NODES * 4;
    int*            bcnt  = (int*)(ws + off);            off += NBUCK * 4;
    int*            incl  = (int*)(ws + off);            off += (size_t)N_NODES * 4;
    int*            offs  = (int*)(ws + off);            off += (size_t)N_NODES * 4;
    int*            bsum  = (int*)(ws + off);            off += 128 * 4;
    int*            srcs  = (int*)(ws + off);            off += (size_t)SRCS_CAP * 4;
    int*            flag  = (int*)(ws + off);            off += 4;

    const int nb_agg    = (N_NODES * 8 + 255) / 256;    // 3125 (8 lanes per node)
    const int nb_aggprj = (N_NODES + 63) / 64;          // 1563 (64 nodes per block)
    const int nb_bucket = (N_EDGES + 2047) / 2048;      // 782

    // detect + zero bcnt/sums/cnts (merged)
    k_detect<<<1, 256, 0, stream>>>(ei, flag, bcnt, sums, cnts);

    // --- CSR build: bucket -> per-bucket hist(+dis) -> scan -> place ---
    k_bucket<<<nb_bucket, 256, 0, stream>>>(ei, flag, pairs, bcnt);
    k_hist<<<NBUCK, 1024, 0, stream>>>(pairs, bcnt, indeg, dis);
    k_scan1<<<NBLK, SCAN_B, 0, stream>>>(indeg, incl, bsum);
    k_scan2<<<1, 128, 0, stream>>>(bsum);
    k_scan3<<<NBLK, SCAN_B, 0, stream>>>(indeg, incl, bsum, offs);
    k_place3<<<NBUCK, 1024, 0, stream>>>(pairs, bcnt, offs, srcs);

    // conv1 projection: x(fp32,128) @ W1 -> Ga(fp8)
    k_proj<128, float><<<512, 256, 0, stream>>>(x, W1, dis, Ga);
    // conv1 agg + conv2 projection fused: Ga -> h1 -> Gb
    k_aggproj<<<nb_aggprj, 256, 0, stream>>>(Ga, srcs, offs, indeg, dis, b1, W2, Gb);
    // conv2 agg + conv3 projection fused: Gb -> h2 -> Ga
    k_aggproj<<<nb_aggprj, 256, 0, stream>>>(Gb, srcs, offs, indeg, dis, b2, W3, Ga);
    // conv3 agg (no relu): Ga -> A(bf16)
    k_agg<false><<<nb_agg, 256, 0, stream>>>(Ga, srcs, offs, indeg, dis, b3, A);

    // pool + head (sums/cnts pre-zeroed in k_detect)
    k_pool<<<N_GRAPHS * 4, 256, 0, stream>>>(A, bat, flag, sums, cnts);
    k_head<<<(N_GRAPHS * N_OUT + 63) / 64, 64, 0, stream>>>(sums, cnts, Wlin, blin, out);
}

// Round 6
// 288.497 us; speedup vs baseline: 1.4976x; 1.1245x over previous
//
#include <hip/hip_runtime.h>
#include <hip/hip_bf16.h>

#define N_NODES 100000
#define N_EDGES 1600000
#define N_FEAT 128
#define HID 64
#define N_GRAPHS 64
#define N_OUT 10
#define SCAN_B 1024
#define NBLK ((N_NODES + SCAN_B - 1) / SCAN_B)  // 98
#define NBUCK 256
#define RANGEB ((N_NODES + NBUCK - 1) / NBUCK)  // 391
#define CAP 8192
#define SRCS_CAP (N_EDGES + 8 * N_NODES)  // padded CSR upper bound

typedef __attribute__((ext_vector_type(8))) short bf8_t;   // 8 bf16 in 4 VGPRs
typedef __attribute__((ext_vector_type(4))) float f4_t;    // MFMA accumulator
typedef __attribute__((ext_vector_type(2))) float f2_t;

__device__ __forceinline__ short f2bf(float f) {
    __hip_bfloat16 h = __float2bfloat16(f);
    return *(short*)&h;
}
__device__ __forceinline__ float bf2f(unsigned short u) {
    unsigned v = ((unsigned)u) << 16;
    return __builtin_bit_cast(float, v);
}
__device__ __forceinline__ unsigned char f2fp8(float v) {
    int p = __builtin_amdgcn_cvt_pk_fp8_f32(v, v, 0, false);
    return (unsigned char)(p & 0xFF);
}
// decode one dword of fp8 into two f2_t accumulators (v_pk_add_f32-friendly)
__device__ __forceinline__ void fp8acc2(f2_t* acc2, unsigned w) {
    acc2[0] += __builtin_amdgcn_cvt_pk_f32_fp8((int)w, false);
    acc2[1] += __builtin_amdgcn_cvt_pk_f32_fp8((int)w, true);
}

__device__ __forceinline__ int ldidx(const int* raw, int f, size_t i) {
    return f ? raw[2 * i] : raw[i];
}

// ---------- index dtype probe + workspace zeroing (merged) ----------
__global__ void k_detect(const int* raw, int* flag, int* bcnt, float* sums, float* cnts) {
    __shared__ int any;
    if (threadIdx.x == 0) any = 0;
    __syncthreads();
    int v = raw[2 * threadIdx.x + 1] | raw[2 * (threadIdx.x + 256) + 1] |
            raw[2 * (threadIdx.x + 512) + 1] | raw[2 * (threadIdx.x + 768) + 1];
    if (v != 0) any = 1;
    __syncthreads();
    if (threadIdx.x == 0) *flag = (any == 0) ? 1 : 0;
    for (int i = threadIdx.x; i < NBUCK; i += 256) bcnt[i] = 0;
    for (int i = threadIdx.x; i < N_GRAPHS * HID; i += 256) sums[i] = 0.f;
    for (int i = threadIdx.x; i < N_GRAPHS; i += 256) cnts[i] = 0.f;
}

// ---------- phase 1: bin edges into 256 col-range buckets (packed 4B entries) ----------
// entry = (local_col << 17) | src   (local_col < 391 -> 9 bits, src <= 100000 -> 17 bits)
__global__ __launch_bounds__(256) void k_bucket(const int* ei, const int* flag,
                                                int* pairs, int* cnt) {
    __shared__ int lcnt[NBUCK];
    __shared__ int gbase[NBUCK];
    int f = *flag;
    if (threadIdx.x < NBUCK) lcnt[threadIdx.x] = 0;
    __syncthreads();
    int base = blockIdx.x * 2048;
    int r[8], lpos[8], c[8], s[8];
#pragma unroll
    for (int i = 0; i < 8; i++) {
        int e = base + i * 256 + threadIdx.x;
        r[i] = -1;
        if (e < N_EDGES) {
            c[i] = ldidx(ei, f, (size_t)N_EDGES + e);
            s[i] = ldidx(ei, f, (size_t)e);
            if ((unsigned)c[i] < N_NODES && (unsigned)s[i] < N_NODES) {
                r[i] = c[i] / RANGEB;
                lpos[i] = atomicAdd(&lcnt[r[i]], 1);
            }
        }
    }
    __syncthreads();
    if (threadIdx.x < NBUCK && lcnt[threadIdx.x] > 0)
        gbase[threadIdx.x] = atomicAdd(&cnt[threadIdx.x], lcnt[threadIdx.x]);
    __syncthreads();
#pragma unroll
    for (int i = 0; i < 8; i++) {
        if (r[i] >= 0) {
            int p = gbase[r[i]] + lpos[i];
            if (p < CAP) {
                int loc = c[i] - r[i] * RANGEB;
                pairs[(size_t)r[i] * CAP + p] = (loc << 17) | s[i];
            }
        }
    }
}

// ---------- per-bucket LDS histogram -> indeg + dis (merged) ----------
__global__ __launch_bounds__(1024) void k_hist(const int* pairs, const int* cnt,
                                               int* indeg, float* dis) {
    __shared__ int hist[RANGEB];
    int b = blockIdx.x;
    int c0 = b * RANGEB;
    int range = min(RANGEB, N_NODES - c0);
    for (int i = threadIdx.x; i < range; i += 1024) hist[i] = 0;
    __syncthreads();
    int n = min(cnt[b], CAP);
    const int* pb = pairs + (size_t)b * CAP;
    for (int i = threadIdx.x; i < n; i += 1024)
        atomicAdd(&hist[pb[i] >> 17], 1);
    __syncthreads();
    for (int i = threadIdx.x; i < range; i += 1024) {
        int d = hist[i];
        indeg[c0 + i] = d;
        dis[c0 + i] = rsqrtf((float)d + 1.0f);
    }
}

// ---------- prefix scan over PADDED degrees ((deg+7)&~7) ----------
__global__ __launch_bounds__(SCAN_B) void k_scan1(const int* indeg, int* incl, int* bsum) {
    __shared__ int tmp[SCAN_B];
    int i = blockIdx.x * SCAN_B + threadIdx.x;
    tmp[threadIdx.x] = (i < N_NODES) ? ((indeg[i] + 7) & ~7) : 0;
    __syncthreads();
    for (int d = 1; d < SCAN_B; d <<= 1) {
        int t = (threadIdx.x >= d) ? tmp[threadIdx.x - d] : 0;
        __syncthreads();
        tmp[threadIdx.x] += t;
        __syncthreads();
    }
    if (i < N_NODES) incl[i] = tmp[threadIdx.x];
    if (threadIdx.x == SCAN_B - 1) bsum[blockIdx.x] = tmp[threadIdx.x];
}

// ---------- scan3 with inline cross-block prefix (k_scan2 merged in) ----------
__global__ __launch_bounds__(SCAN_B) void k_scan3(const int* indeg, const int* incl,
                                                  const int* bsum, int* offs) {
    __shared__ int pre_s;
    if (threadIdx.x < 64) {
        int acc = 0;
        for (int i = threadIdx.x; i < NBLK; i += 64)
            if (i < blockIdx.x) acc += bsum[i];
#pragma unroll
        for (int m = 1; m < 64; m <<= 1) acc += __shfl_xor(acc, m);
        if (threadIdx.x == 0) pre_s = acc;
    }
    __syncthreads();
    int i = blockIdx.x * SCAN_B + threadIdx.x;
    if (i < N_NODES) {
        int pdeg = (indeg[i] + 7) & ~7;
        offs[i] = incl[i] - pdeg + pre_s;
    }
}

// ---------- per-bucket CSR placement via LDS cursors + pad fill ----------
__global__ __launch_bounds__(1024) void k_place3(const int* pairs, const int* cnt,
                                                 const int* offs, int* srcs) {
    __shared__ int cur[RANGEB];
    int b = blockIdx.x;
    int c0 = b * RANGEB;
    int range = min(RANGEB, N_NODES - c0);
    for (int i = threadIdx.x; i < range; i += 1024) cur[i] = 0;
    __syncthreads();
    int n = min(cnt[b], CAP);
    const int* pb = pairs + (size_t)b * CAP;
    for (int i = threadIdx.x; i < n; i += 1024) {
        int v = pb[i];
        int loc = v >> 17;
        int p = offs[c0 + loc] + atomicAdd(&cur[loc], 1);
        srcs[p] = v & 0x1FFFF;
    }
    __syncthreads();
    for (int i = threadIdx.x; i < range; i += 1024) {
        int deg = cur[i];
        int pdeg = (deg + 7) & ~7;
        int o = offs[c0 + i];
        for (int k = deg; k < pdeg; k++) srcs[o + k] = N_NODES;  // pad -> zero row
    }
}

// ---------- projection via MFMA: g[i,:] = fp8( dis[i] * (h[i,:] @ W) ) ----------
template <int K, typename IT>
__global__ __launch_bounds__(256) void k_proj(const IT* __restrict__ in,
                                              const float* __restrict__ W,
                                              const float* __restrict__ dis,
                                              unsigned char* __restrict__ g) {
    // zero the pad row (row N_NODES, 64 B) -- pad edge slots in k_agg read it
    if (blockIdx.x == 0 && threadIdx.x < 16)
        ((unsigned*)g)[N_NODES * 16 + threadIdx.x] = 0u;
    const int NS = K / 32;
    int wave = threadIdx.x >> 6, lane = threadIdx.x & 63;
    int m = lane & 15, quad = lane >> 4;
    bf8_t Bf[NS][4];
#pragma unroll
    for (int s = 0; s < NS; s++)
#pragma unroll
        for (int t = 0; t < 4; t++)
#pragma unroll
            for (int j = 0; j < 8; j++)
                Bf[s][t][j] = f2bf(W[(s * 32 + quad * 8 + j) * 64 + t * 16 + m]);

    const int nchunks = N_NODES / 16;  // 6250
    const int stride = gridDim.x * 4;
    for (int chunk = blockIdx.x * 4 + wave; chunk < nchunks; chunk += stride) {
        int r0 = chunk * 16;
        const IT* src = in + (size_t)(r0 + m) * K + quad * 8;
        f4_t acc[4] = {{0.f, 0.f, 0.f, 0.f}, {0.f, 0.f, 0.f, 0.f},
                       {0.f, 0.f, 0.f, 0.f}, {0.f, 0.f, 0.f, 0.f}};
#pragma unroll
        for (int s = 0; s < NS; s++) {
            bf8_t a;
            if constexpr (sizeof(IT) == 2) {
                a = *(const bf8_t*)(src + s * 32);
            } else {
                const float4* sp = (const float4*)(src + s * 32);
                float4 u0 = sp[0], u1 = sp[1];
                a[0] = f2bf(u0.x); a[1] = f2bf(u0.y); a[2] = f2bf(u0.z); a[3] = f2bf(u0.w);
                a[4] = f2bf(u1.x); a[5] = f2bf(u1.y); a[6] = f2bf(u1.z); a[7] = f2bf(u1.w);
            }
#pragma unroll
            for (int t = 0; t < 4; t++)
                acc[t] = __builtin_amdgcn_mfma_f32_16x16x32_bf16(a, Bf[s][t], acc[t], 0, 0, 0);
        }
        float dv[4];
#pragma unroll
        for (int i = 0; i < 4; i++) dv[i] = dis[r0 + quad * 4 + i];
#pragma unroll
        for (int t = 0; t < 4; t++)
#pragma unroll
            for (int i = 0; i < 4; i++)
                g[(size_t)(r0 + quad * 4 + i) * 64 + t * 16 + m] = f2fp8(dv[i] * acc[t][i]);
    }
}

// ---------- CSR aggregation: 8 nodes/wave, 8 lanes (= feature groups)/node ----------
// Padded CSR (offs 8-aligned, pads -> zero row): the group's next 8 edge indices
// come from two aligned int4 loads (same addr across the 8 lanes = broadcast),
// no ds_swizzle / no per-edge predication -> pure-vmem dependency graph.
template <bool RELU>
__global__ __launch_bounds__(256) void k_agg(const unsigned char* __restrict__ g,
                                             const int* __restrict__ srcs,
                                             const int* __restrict__ offs,
                                             const int* __restrict__ indeg,
                                             const float* __restrict__ dis,
                                             const float* __restrict__ b,
                                             unsigned short* __restrict__ out) {
    int node = (blockIdx.x * 256 + threadIdx.x) >> 3;
    int fg = threadIdx.x & 7;
    if (node >= N_NODES) return;
    int beg = offs[node];
    int pdeg = (indeg[node] + 7) & ~7;
    const unsigned char* gf = g + fg * 8;
    f2_t acc2[4] = {{0.f, 0.f}, {0.f, 0.f}, {0.f, 0.f}, {0.f, 0.f}};
    {  // self loop
        uint2 w = *(const uint2*)(gf + (size_t)node * 64);
        fp8acc2(acc2, w.x);
        fp8acc2(acc2 + 2, w.y);
    }
    for (int e0 = 0; e0 < pdeg; e0 += 8) {
        int4 u = *(const int4*)(srcs + beg + e0);      // 16B-aligned (beg%8==0)
        int4 v = *(const int4*)(srcs + beg + e0 + 4);
#define AGG_DO(ii)                                                            \
        {                                                                     \
            uint2 w = *(const uint2*)(gf + (size_t)(ii) * 64);                \
            fp8acc2(acc2, w.x);                                               \
            fp8acc2(acc2 + 2, w.y);                                           \
        }
        AGG_DO(u.x) AGG_DO(u.y) AGG_DO(u.z) AGG_DO(u.w)
        AGG_DO(v.x) AGG_DO(v.y) AGG_DO(v.z) AGG_DO(v.w)
#undef AGG_DO
    }
    float dv = dis[node];
    unsigned o[4];
#pragma unroll
    for (int p = 0; p < 4; p++) {
        float v0 = dv * acc2[p][0] + b[fg * 8 + 2 * p];
        float v1 = dv * acc2[p][1] + b[fg * 8 + 2 * p + 1];
        if (RELU) { v0 = fmaxf(v0, 0.f); v1 = fmaxf(v1, 0.f); }
        o[p] = ((unsigned)(unsigned short)f2bf(v1) << 16) | (unsigned short)f2bf(v0);
    }
    *(uint4*)((char*)out + (size_t)node * 128 + fg * 16) =
        make_uint4(o[0], o[1], o[2], o[3]);
}

// ---------- pooling: 4 blocks per graph, binary-search boundaries, LDS reduce ----------
__global__ __launch_bounds__(256) void k_pool(const unsigned short* h, const int* bat,
                                              const int* flag, float* sums, float* cnts) {
    __shared__ int sb[2];
    __shared__ float red[4][64];
    int g = blockIdx.x >> 2;
    int q = blockIdx.x & 3;
    if (threadIdx.x == 0) {
        int f = *flag;
        int lo = 0, hi = N_NODES;
        while (lo < hi) { int mid = (lo + hi) >> 1; if (ldidx(bat, f, (size_t)mid) < g) lo = mid + 1; else hi = mid; }
        sb[0] = lo;
        hi = N_NODES;
        while (lo < hi) { int mid = (lo + hi) >> 1; if (ldidx(bat, f, (size_t)mid) < g + 1) lo = mid + 1; else hi = mid; }
        sb[1] = lo;
    }
    __syncthreads();
    int gs = sb[0], ge = sb[1];
    int len = ge - gs;
    if (q == 0 && threadIdx.x == 0) cnts[g] = (float)len;
    if (len == 0) return;
    int qlen = (len + 3) >> 2;
    int beg = gs + q * qlen, end = min(ge, beg + qlen);
    int wave = threadIdx.x >> 6, lane = threadIdx.x & 63;
    float acc = 0.f;
    for (int r = beg + wave; r < end; r += 4)
        acc += bf2f(h[(size_t)r * 64 + lane]);
    red[wave][lane] = acc;
    __syncthreads();
    if (threadIdx.x < 64) {
        float v = red[0][threadIdx.x] + red[1][threadIdx.x] +
                  red[2][threadIdx.x] + red[3][threadIdx.x];
        atomicAdd(&sums[g * 64 + threadIdx.x], v);
    }
}

// ---------- head ----------
__global__ void k_head(const float* sums, const float* cnts, const float* Wlin,
                       const float* blin, float* out) {
    int t = blockIdx.x * 64 + threadIdx.x;
    if (t < N_GRAPHS * N_OUT) {
        int gph = t / N_OUT, o = t % N_OUT;
        float c = fmaxf(cnts[gph], 1.0f);
        float a = 0.f;
        for (int j = 0; j < HID; j++) a += sums[gph * 64 + j] * Wlin[j * N_OUT + o];
        out[t] = a / c + blin[o];
    }
}

extern "C" void kernel_launch(void* const* d_in, const int* in_sizes, int n_in,
                              void* d_out, int out_size, void* d_ws, size_t ws_size,
                              hipStream_t stream) {
    const float *x = nullptr, *W1 = nullptr, *W2 = nullptr, *W3 = nullptr, *Wlin = nullptr;
    const float *b1 = nullptr, *b2 = nullptr, *b3 = nullptr, *blin = nullptr;
    const int *ei = nullptr, *bat = nullptr;
    int n4096 = 0, n64 = 0;
    for (int i = 0; i < n_in; i++) {
        switch (in_sizes[i]) {
            case N_NODES * N_FEAT:  x    = (const float*)d_in[i]; break;
            case 2 * N_EDGES:       ei   = (const int*)d_in[i];   break;
            case N_NODES:           bat  = (const int*)d_in[i];   break;
            case N_FEAT * HID:      W1   = (const float*)d_in[i]; break;
            case HID * HID:
                if (n4096++ == 0) W2 = (const float*)d_in[i];
                else              W3 = (const float*)d_in[i];
                break;
            case HID * N_OUT:       Wlin = (const float*)d_in[i]; break;
            case HID:
                if (n64 == 0) b1 = (const float*)d_in[i];
                else if (n64 == 1) b2 = (const float*)d_in[i];
                else b3 = (const float*)d_in[i];
                n64++;
                break;
            case N_OUT:             blin = (const float*)d_in[i]; break;
            default: break;
        }
    }
    if (!x || !ei || !bat || !W1 || !W2 || !W3 || !Wlin || !b1 || !b2 || !b3 || !blin) {
        x    = (const float*)d_in[0];
        ei   = (const int*)d_in[1];
        bat  = (const int*)d_in[2];
        W1   = (const float*)d_in[3];  b1   = (const float*)d_in[4];
        W2   = (const float*)d_in[5];  b2   = (const float*)d_in[6];
        W3   = (const float*)d_in[7];  b3   = (const float*)d_in[8];
        Wlin = (const float*)d_in[9];  blin = (const float*)d_in[10];
    }
    float* out = (float*)d_out;  // fp32 output

    char* ws = (char*)d_ws;
    size_t off = 0;
    int*            pairs = (int*)(ws + off);            off += (size_t)NBUCK * CAP * 4;
    unsigned short* A     = (unsigned short*)(ws + off); off += (size_t)N_NODES * 64 * 2;
    unsigned char*  G     = (unsigned char*)(ws + off);  off += (size_t)(N_NODES + 1) * 64;
    float*          dis   = (float*)(ws + off);          off += (size_t)N_NODES * 4;
    float*          sums  = (float*)(ws + off);          off += (size_t)N_GRAPHS * HID * 4;
    float*          cnts  = (float*)(ws + off);          off += (size_t)N_GRAPHS * 4;
    int*            indeg = (int*)(ws + off);            off += (size_t)N_NODES * 4;
    int*            bcnt  = (int*)(ws + off);            off += NBUCK * 4;
    int*            incl  = (int*)(ws + off);            off += (size_t)N_NODES * 4;
    int*            offs  = (int*)(ws + off);            off += (size_t)N_NODES * 4;
    int*            bsum  = (int*)(ws + off);            off += 128 * 4;
    int*            srcs  = (int*)(ws + off);            off += (size_t)SRCS_CAP * 4;
    int*            flag  = (int*)(ws + off);            off += 4;

    const int nb_agg    = (N_NODES * 8 + 255) / 256;    // 3125 (8 lanes per node)
    const int nb_bucket = (N_EDGES + 2047) / 2048;      // 782

    // detect + zero bcnt/sums/cnts (merged)
    k_detect<<<1, 256, 0, stream>>>(ei, flag, bcnt, sums, cnts);

    // --- CSR build: bucket -> per-bucket hist(+dis) -> scan -> place ---
    k_bucket<<<nb_bucket, 256, 0, stream>>>(ei, flag, pairs, bcnt);
    k_hist<<<NBUCK, 1024, 0, stream>>>(pairs, bcnt, indeg, dis);
    k_scan1<<<NBLK, SCAN_B, 0, stream>>>(indeg, incl, bsum);
    k_scan3<<<NBLK, SCAN_B, 0, stream>>>(indeg, incl, bsum, offs);
    k_place3<<<NBUCK, 1024, 0, stream>>>(pairs, bcnt, offs, srcs);

    // conv1: x(fp32,128) -> G(fp8) -> A(bf16)
    k_proj<128, float><<<512, 256, 0, stream>>>(x, W1, dis, G);
    k_agg<true><<<nb_agg, 256, 0, stream>>>(G, srcs, offs, indeg, dis, b1, A);

    // conv2: A -> G -> A
    k_proj<64, unsigned short><<<512, 256, 0, stream>>>(A, W2, dis, G);
    k_agg<true><<<nb_agg, 256, 0, stream>>>(G, srcs, offs, indeg, dis, b2, A);

    // conv3: A -> G -> A (no relu)
    k_proj<64, unsigned short><<<512, 256, 0, stream>>>(A, W3, dis, G);
    k_agg<false><<<nb_agg, 256, 0, stream>>>(G, srcs, offs, indeg, dis, b3, A);

    // pool + head (sums/cnts pre-zeroed in k_detect)
    k_pool<<<N_GRAPHS * 4, 256, 0, stream>>>(A, bat, flag, sums, cnts);
    k_head<<<(N_GRAPHS * N_OUT + 63) / 64, 64, 0, stream>>>(sums, cnts, Wlin, blin, out);
}